// Round 12
// baseline (245.191 us; speedup 1.0000x reference)
//
#include <hip/hip_runtime.h>
#include <hip/hip_fp16.h>

// Problem constants
#define TT   512
#define DD   64
#define NWK  4
#define STP  16
#define NPJ  15          // others per w
#define NBLK 60          // NWK * NPJ
#define CMAT (TT * TT)   // elements per cost matrix
// u-domain scale: u = R / (gamma * ln2), gamma = 5
#define CSCALE 0.2885390081777927f
#define USCALE 3.4657359027997265f   // gamma * ln2
#define BIGC   2.885390081777927e8f  // 1e9 * CSCALE

#define SA 132           // LDS leading stride (128 + 4 pad)
#define SMEMSZ (2 * DD * SA * 4 + 1024)   // 68608 B: As+Bs + a2+b2 (union arena)

// ---------------------------------------------------------------------------
// Soft-DTW DP cell in u-units: u = dc + min - log2(1 + 2^(min-med) + 2^(min-max))
// ---------------------------------------------------------------------------
__device__ __forceinline__ float dpcell(float dc, float a, float b, float c) {
  float mn = fminf(fminf(a, b), c);
  float mx = fmaxf(fmaxf(a, b), c);
  float md = __builtin_amdgcn_fmed3f(a, b, c);
  float e = 1.0f + __builtin_amdgcn_exp2f(mn - md) + __builtin_amdgcn_exp2f(mn - mx);
  return dc + mn - __builtin_amdgcn_logf(e);
}

// DPP wave_shr:1 — VALU-latency replacement for __shfl_up(x, 1).
__device__ __forceinline__ float wave_shr1(float x) {
  int xi = __float_as_int(x);
  int r = __builtin_amdgcn_update_dpp(xi, xi, 0x138 /*wave_shr:1*/, 0xF, 0xF, false);
  return __int_as_float(r);
}

__global__ __launch_bounds__(64) void zero_kernel(int* __restrict__ cnt) {
  cnt[threadIdx.x] = 0;
}

// ---------------------------------------------------------------------------
// Mega kernel: one dispatch carrying three block roles, so the latency-bound
// DP chains overlap with the throughput-bound cost tiles and gram blocks:
//   [0, n)            : DP block for matrix mloc = b (spins on cnt[mloc]==16)
//   [n, n+ng)         : gram block (first chunk only)
//   [n+ng, n+ng+16n)  : cost tile block (matrix-major: mloc = cb>>4)
// Gating: cost blocks do syncthreads -> threadfence (agent release, flushes
// XCD L2) -> atomicAdd(cnt+mloc) [device scope]; DP thread0 spins with
// AGENT-acquire atomic load, then threadfence (invalidate) + barrier.
// Deadlock-free: dp+gram blocks (<=181) each hold one of 2 per-CU slots
// (68.6KB/160KB LDS), so every CU always has a slot for cost blocks.
// ---------------------------------------------------------------------------
__global__ __launch_bounds__(256) void mega_kernel(const float* __restrict__ data,
                                                   const int* __restrict__ lens,
                                                   __half* __restrict__ cost,
                                                   float* __restrict__ sdt,
                                                   float* __restrict__ gram,
                                                   int* __restrict__ cnt,
                                                   int base, int n, int ng) {
  __shared__ __align__(16) char smem[SMEMSZ];
  int b = blockIdx.x;

  if (b >= n + ng) {
    // ------------------------- cost tile path -------------------------
    int cb = b - n - ng;
    int mloc = cb >> 4, tile = cb & 15;
    int blk = base + mloc;
    int w = blk / NPJ, j = blk - w * NPJ;
    int la = lens[w * STP];
    int lb = lens[w * STP + 1 + j];
    int ti = tile >> 2, tj = tile & 3;
    if (ti * 128 >= la || tj * 128 >= lb) {
      if (threadIdx.x == 0) atomicAdd(&cnt[mloc], 1);   // dead tile: count only
      return;
    }

    float (*As)[SA] = (float(*)[SA])smem;
    float (*Bs)[SA] = (float(*)[SA])(smem + DD * SA * 4);
    float* a2 = (float*)(smem + 2 * DD * SA * 4);
    float* b2 = a2 + 128;

    const float* A = data + ((size_t)(w * STP) * TT + (size_t)ti * 128) * DD;
    const float* B = data + ((size_t)(w * STP + 1 + j) * TT + (size_t)tj * 128) * DD;
    int t = threadIdx.x;

    #pragma unroll
    for (int i = 0; i < 8; ++i) {
      int idx = t + i * 256;        // [0, 2048)
      int r = idx & 127;            // row within tile
      int kq = idx >> 7;            // float4 index along k, [0,16)
      float4 va = *(const float4*)(A + r * DD + kq * 4);
      As[kq * 4 + 0][r] = va.x; As[kq * 4 + 1][r] = va.y;
      As[kq * 4 + 2][r] = va.z; As[kq * 4 + 3][r] = va.w;
      float4 vb = *(const float4*)(B + r * DD + kq * 4);
      Bs[kq * 4 + 0][r] = vb.x; Bs[kq * 4 + 1][r] = vb.y;
      Bs[kq * 4 + 2][r] = vb.z; Bs[kq * 4 + 3][r] = vb.w;
    }
    __syncthreads();
    if (t < 128) {
      float s = 0.f;
      for (int k = 0; k < DD; ++k) { float x = As[k][t]; s += x * x; }
      a2[t] = s;
    } else {
      float s = 0.f;
      for (int k = 0; k < DD; ++k) { float x = Bs[k][t - 128]; s += x * x; }
      b2[t - 128] = s;
    }
    __syncthreads();

    int r0 = (t >> 4) << 2;   // {0,4,...,60}
    int c0 = (t & 15) << 2;   // {0,4,...,60}
    float acc[8][8];
    #pragma unroll
    for (int i = 0; i < 8; ++i)
      #pragma unroll
      for (int q = 0; q < 8; ++q) acc[i][q] = 0.f;

    #pragma unroll 2
    for (int k = 0; k < DD; ++k) {
      float4 aL = *(const float4*)&As[k][r0];
      float4 aH = *(const float4*)&As[k][r0 + 64];
      float4 bL = *(const float4*)&Bs[k][c0];
      float4 bH = *(const float4*)&Bs[k][c0 + 64];
      float a[8] = {aL.x, aL.y, aL.z, aL.w, aH.x, aH.y, aH.z, aH.w};
      float bq[8] = {bL.x, bL.y, bL.z, bL.w, bH.x, bH.y, bH.z, bH.w};
      #pragma unroll
      for (int i = 0; i < 8; ++i)
        #pragma unroll
        for (int q = 0; q < 8; ++q)
          acc[i][q] += a[i] * bq[q];
    }

    __half* Cbase = cost + (size_t)mloc * CMAT;
    #pragma unroll
    for (int i = 0; i < 8; ++i) {
      int rr = (i < 4) ? (r0 + i) : (r0 + 60 + i);   // r0+64+(i-4)
      float ar = a2[rr];
      __half* Crow = Cbase + (size_t)(ti * 128 + rr) * TT + tj * 128;
      float4 o;
      o.x = (ar + b2[c0 + 0] - 2.f * acc[i][0]) * CSCALE;
      o.y = (ar + b2[c0 + 1] - 2.f * acc[i][1]) * CSCALE;
      o.z = (ar + b2[c0 + 2] - 2.f * acc[i][2]) * CSCALE;
      o.w = (ar + b2[c0 + 3] - 2.f * acc[i][3]) * CSCALE;
      __half2 h01 = __floats2half2_rn(o.x, o.y);
      __half2 h23 = __floats2half2_rn(o.z, o.w);
      uint2 pk; pk.x = *(unsigned*)&h01; pk.y = *(unsigned*)&h23;
      *(uint2*)(Crow + c0) = pk;
      float4 o2;
      o2.x = (ar + b2[c0 + 64] - 2.f * acc[i][4]) * CSCALE;
      o2.y = (ar + b2[c0 + 65] - 2.f * acc[i][5]) * CSCALE;
      o2.z = (ar + b2[c0 + 66] - 2.f * acc[i][6]) * CSCALE;
      o2.w = (ar + b2[c0 + 67] - 2.f * acc[i][7]) * CSCALE;
      __half2 g01 = __floats2half2_rn(o2.x, o2.y);
      __half2 g23 = __floats2half2_rn(o2.z, o2.w);
      uint2 pk2; pk2.x = *(unsigned*)&g01; pk2.y = *(unsigned*)&g23;
      *(uint2*)(Crow + c0 + 64) = pk2;
    }
    __syncthreads();                     // all stores done (barrier drains vmcnt)
    if (threadIdx.x == 0) {
      __threadfence();                   // agent release: flush XCD L2 -> coherent point
      atomicAdd(&cnt[mloc], 1);          // device-scope publish
    }
    return;
  }

  if (b >= n) {
    // ---------------- gram path: 44x44 Gram over K = 32768 ----------------
    float (*red)[16] = (float(*)[16])smem;
    int g = b - n;
    int bx = g / 11, by = g - bx * 11;
    int t = threadIdx.x;
    const float* Ar[4]; const float* Br[4];
    #pragma unroll
    for (int a = 0; a < 4; ++a) {
      int gx = bx * 4 + a;
      Ar[a] = data + (size_t)((gx / 11) * STP + gx % 11) * (TT * DD);
      int gy = by * 4 + a;
      Br[a] = data + (size_t)((gy / 11) * STP + gy % 11) * (TT * DD);
    }
    float acc[4][4];
    #pragma unroll
    for (int a = 0; a < 4; ++a)
      #pragma unroll
      for (int bq = 0; bq < 4; ++bq) acc[a][bq] = 0.f;
    for (int k = t * 4; k < TT * DD; k += 1024) {
      float4 av[4], bv[4];
      #pragma unroll
      for (int a = 0; a < 4; ++a) av[a] = *(const float4*)(Ar[a] + k);
      #pragma unroll
      for (int bq = 0; bq < 4; ++bq) bv[bq] = *(const float4*)(Br[bq] + k);
      #pragma unroll
      for (int a = 0; a < 4; ++a)
        #pragma unroll
        for (int bq = 0; bq < 4; ++bq)
          acc[a][bq] += av[a].x * bv[bq].x + av[a].y * bv[bq].y +
                        av[a].z * bv[bq].z + av[a].w * bv[bq].w;
    }
    int wave = t >> 6, lane = t & 63;
    #pragma unroll
    for (int a = 0; a < 4; ++a)
      #pragma unroll
      for (int bq = 0; bq < 4; ++bq) {
        float v = acc[a][bq];
        for (int off = 32; off > 0; off >>= 1) v += __shfl_down(v, off);
        if (lane == 0) red[wave][a * 4 + bq] = v;
      }
    __syncthreads();
    if (t < 16) {
      float v = red[0][t] + red[1][t] + red[2][t] + red[3][t];
      int a = t >> 2, bq = t & 3;
      gram[(size_t)(bx * 4 + a) * 44 + by * 4 + bq] = v;
    }
    return;
  }

  // -------------------------- DP path --------------------------
  int mloc = b;
  if (threadIdx.x == 0) {
    while (__hip_atomic_load(&cnt[mloc], __ATOMIC_ACQUIRE, __HIP_MEMORY_SCOPE_AGENT) < 16)
      __builtin_amdgcn_s_sleep(2);
  }
  __syncthreads();
  __threadfence();                       // acquire: invalidate stale L1/L2

  float (*bufB)[600] = (float(*)[600])smem;   // boundary columns (write-once)
  int* flags = (int*)(smem + 3 * 600 * 4);

  if (threadIdx.x < 4) flags[threadIdx.x] = 0;
  __syncthreads();

  int blk = base + mloc;
  int w = blk / NPJ, j = blk - w * NPJ;
  int la = lens[w * STP];
  int lb = lens[w * STP + 1 + j];
  const __half* C = cost + (size_t)mloc * CMAT;

  int q = threadIdx.x >> 6, ln = threadIdx.x & 63;
  int c0 = q * 128 + ln * 2;
  const __half* Cp = C + c0;

  // target cell (la-1, lb-1)
  int qt = (lb - 1) >> 7;
  int lt = ((lb - 1) >> 1) & 63;
  int par = (lb - 1) & 1;
  int rt = la - 1;
  bool isT = (q == qt) && (ln == lt);

  float U0 = BIGC, U1 = BIGC;          // own cols, previous row
  float NL = BIGC;                     // left neighbor value, current row
  float NLd = (q == 0 && ln == 0) ? 0.0f : BIGC;  // left-diag (prev row)
  float v1s = BIGC;                    // last computed right-col value
  float res = 0.0f;

  int ngrp = (la + 70) >> 3;

  // cc = current group f32; cn = RAW half2 bits prefetch (no consumer in the
  // prefetch phase -> loads stay in flight; convert at group-end copy)
  float2 cc[8];
  unsigned cn[8];
  #pragma unroll
  for (int k = 0; k < 8; ++k) {
    int rr = k - ln; rr = rr < 0 ? 0 : (rr > 511 ? 511 : rr);
    __half2 hv = *(const __half2*)(Cp + (size_t)rr * TT);
    cc[k] = __half22float2(hv);
  }
  float bb[8];

  for (int g = 0; g < ngrp; ++g) {
    if (q > 0) {
      int need = 8 * g + 9; if (need > la) need = la;
      while (*(volatile int*)&flags[q - 1] < need) __builtin_amdgcn_s_sleep(1);
      asm volatile("s_waitcnt lgkmcnt(0)" ::: "memory");
      #pragma unroll
      for (int k = 0; k < 8; ++k) bb[k] = bufB[q - 1][8 * g + 1 + k];
      if (g == 0) {
        float nl0 = bufB[q - 1][0];
        if (ln == 0) NL = nl0;
      }
    }
    // prefetch RAW bits for next group
    #pragma unroll
    for (int k = 0; k < 8; ++k) {
      int rr = 8 * (g + 1) + k - ln; rr = rr < 0 ? 0 : (rr > 511 ? 511 : rr);
      cn[k] = *(const unsigned*)(Cp + (size_t)rr * TT);
    }
    #pragma unroll
    for (int k = 0; k < 8; ++k) {
      int r = 8 * g + k - ln;
      bool act = ((unsigned)r < 512u);
      if (act) {
        float v0 = dpcell(cc[k].x, NLd, U0, NL);
        float v1 = dpcell(cc[k].y, U0, U1, v0);
        if (isT & (r == rt)) res = par ? v1 : v0;
        NLd = NL; U0 = v0; U1 = v1; v1s = v1;
        if (q < 3 && ln == 63) {
          bufB[q][r] = v1;
          if ((r & 7) == 0) {
            // lane63 hits r%8==0 at k=7 (group end); LDS-only ordering wait
            asm volatile("s_waitcnt lgkmcnt(0)" ::: "memory");
            *(volatile int*)&flags[q] = r + 1;
          }
        }
      }
      float nb = wave_shr1(v1s);
      if (ln == 0) nb = (q == 0) ? BIGC : bb[k];
      NL = nb;
    }
    // group-end: convert raw bits -> f32 (waitcnt lands here, loads are done)
    #pragma unroll
    for (int k = 0; k < 8; ++k) {
      __half2 hv = *(__half2*)&cn[k];
      cc[k] = __half22float2(hv);
    }
  }
  if (q < 3 && ln == 63) {
    asm volatile("s_waitcnt lgkmcnt(0)" ::: "memory");
    *(volatile int*)&flags[q] = 512;   // release any remaining pollers
  }
  if (isT) sdt[blk] = res * USCALE;
}

// ---------------------------------------------------------------------------
// Final combine. block 640 = 10 waves; waves 0..8: one MMD pair each;
// wave 9: triplet losses; thread 0 writes the scalar.
// ---------------------------------------------------------------------------
__global__ __launch_bounds__(640) void final_kernel(const float* __restrict__ sdt,
                                                    const int* __restrict__ lens,
                                                    const float* __restrict__ gram,
                                                    float* __restrict__ out) {
  __shared__ float partial[16];
  int t = threadIdx.x, wave = t >> 6, lane = t & 63;
  if (wave < 9) {
    const int piA[9] = {0, 0, 0, 1, 1, 2, 2, 3, 3};
    const int pjA[9] = {1, 2, 3, 2, 3, 1, 3, 1, 2};
    int P = piA[wave], Q = pjA[wave];
    float s1 = 0.f;
    for (int c = lane; c < 484; c += 64) {
      int i = c / 22, jj = c - (c / 22) * 22;
      int gi = (i < 11) ? P * 11 + i : Q * 11 + (i - 11);
      int gj = (jj < 11) ? P * 11 + jj : Q * 11 + (jj - 11);
      s1 += gram[gi * 44 + gi] + gram[gj * 44 + gj] - 2.f * gram[gi * 44 + gj];
    }
    for (int off = 32; off > 0; off >>= 1) s1 += __shfl_down(s1, off);
    s1 = __shfl(s1, 0);
    float bw = s1 / 462.0f * 0.25f;     // /(ns^2-ns) then / KMUL^(KNUM//2)=4
    float inv[5];
    float b = bw;
    #pragma unroll
    for (int qq = 0; qq < 5; ++qq) { inv[qq] = -1.0f / b; b *= 2.0f; }
    float s2 = 0.f;
    for (int c = lane; c < 484; c += 64) {
      int i = c / 22, jj = c - (c / 22) * 22;
      int gi = (i < 11) ? P * 11 + i : Q * 11 + (i - 11);
      int gj = (jj < 11) ? P * 11 + jj : Q * 11 + (jj - 11);
      float l2 = gram[gi * 44 + gi] + gram[gj * 44 + gj] - 2.f * gram[gi * 44 + gj];
      float kk = 0.f;
      #pragma unroll
      for (int qq = 0; qq < 5; ++qq) kk += __expf(l2 * inv[qq]);
      float sgn = ((i < 11) == (jj < 11)) ? 1.0f : -1.0f;
      s2 += sgn * kk;
    }
    for (int off = 32; off > 0; off >>= 1) s2 += __shfl_down(s2, off);
    if (lane == 0) partial[wave] = s2 / 121.0f;
  } else {
    float term = 0.f;
    if (wave == 9 && lane < 4) {
      int w = lane;
      float L0 = (float)lens[w * STP];
      float dist[15];
      for (int qq = 0; qq < 15; ++qq)
        dist[qq] = sdt[w * NPJ + qq] / (L0 + (float)lens[w * STP + 1 + qq]);
      float ca = 0.f, cb = 0.f;
      for (int a = 0; a < 6; ++a) ca += dist[a];
      ca *= (1.0f / 6.0f);
      for (int bq = 6; bq < 11; ++bq) cb += dist[bq];
      cb *= (1.0f / 5.0f);
      float lksum = 0.f; int nz = 0;
      for (int a = 0; a < 6; ++a)
        for (int bq = 6; bq < 15; ++bq) {
          float x = dist[a] + 1.0f - dist[bq];   // MARGIN = 1.0
          if (x > 0.f) { lksum += x; nz += 1; }
        }
      float intra = 0.f;
      for (int a = 0; a < 6; ++a) intra += dist[a] - ca;
      float inter = fmaxf(0.f, 1.0f - fabsf(ca - cb));  // BETA = 1.0
      term = lksum / (float)(nz + 1) + intra * 0.1f + inter * 0.1f;  // P=R=0.1
    }
    if (wave == 9) {
      term += __shfl_down(term, 1);
      term += __shfl_down(term, 2);
      if (lane == 0) partial[9] = term * 0.25f;   // mean over NW=4
    }
  }
  __syncthreads();
  if (t == 0) {
    float mx = 0.0f;                               // zero-pad in the max
    for (int p = 0; p < 9; ++p) mx = fmaxf(mx, partial[p]);
    out[0] = partial[9] + 0.01f * mx;              // ALPHA = 0.01
  }
}

// ---------------------------------------------------------------------------
extern "C" void kernel_launch(void* const* d_in, const int* in_sizes, int n_in,
                              void* d_out, int out_size, void* d_ws, size_t ws_size,
                              hipStream_t stream) {
  const float* data = (const float*)d_in[0];
  const int* lens = (const int*)d_in[1];
  float* out = (float*)d_out;

  float* sdtb  = (float*)d_ws;                      // 64 floats
  float* gramb = sdtb + 64;                         // 44*44 = 1936 floats (ends @ 8000B)
  int*   cntb  = (int*)((char*)d_ws + 8192);        // 64 ints
  __half* costh = (__half*)((char*)d_ws + 8448);    // fp16 cost matrices

  size_t avail = (ws_size > 8448) ? (ws_size - 8448) : 0;
  int chunk = (int)(avail / ((size_t)CMAT * sizeof(__half)));
  if (chunk < 1) chunk = 1;
  if (chunk > NBLK) chunk = NBLK;

  bool first = true;
  for (int base = 0; base < NBLK; base += chunk) {
    int n = NBLK - base;
    if (n > chunk) n = chunk;
    int ng = first ? 121 : 0;
    zero_kernel<<<1, 64, 0, stream>>>(cntb);
    mega_kernel<<<n + ng + 16 * n, 256, 0, stream>>>(data, lens, costh, sdtb, gramb,
                                                     cntb, base, n, ng);
    first = false;
  }
  final_kernel<<<1, 640, 0, stream>>>(sdtb, lens, gramb, out);
}

// Round 13
// 239.476 us; speedup vs baseline: 1.0239x; 1.0239x over previous
//
#include <hip/hip_runtime.h>
#include <hip/hip_fp16.h>

// Problem constants
#define TT   512
#define DD   64
#define NWK  4
#define STP  16
#define NPJ  15          // others per w
#define NBLK 60          // NWK * NPJ
#define CMAT (TT * TT)   // elements per cost matrix
// u-domain scale: u = R / (gamma * ln2), gamma = 5
#define CSCALE 0.2885390081777927f
#define USCALE 3.4657359027997265f   // gamma * ln2
#define BIGC   2.885390081777927e8f  // 1e9 * CSCALE

#define SA 132           // LDS leading stride in halves (128 + 4 pad)
#define SMEMSZ (2 * DD * SA * 2 + 1024)   // 34816 B: fp16 As+Bs + f32 a2+b2 -> 4 blocks/CU

// ---------------------------------------------------------------------------
// Soft-DTW DP cell in u-units: u = dc + min - log2(1 + 2^(min-med) + 2^(min-max))
// ---------------------------------------------------------------------------
__device__ __forceinline__ float dpcell(float dc, float a, float b, float c) {
  float mn = fminf(fminf(a, b), c);
  float mx = fmaxf(fmaxf(a, b), c);
  float md = __builtin_amdgcn_fmed3f(a, b, c);
  float e = 1.0f + __builtin_amdgcn_exp2f(mn - md) + __builtin_amdgcn_exp2f(mn - mx);
  return dc + mn - __builtin_amdgcn_logf(e);
}

// DPP wave_shr:1 — VALU-latency replacement for __shfl_up(x, 1).
__device__ __forceinline__ float wave_shr1(float x) {
  int xi = __float_as_int(x);
  int r = __builtin_amdgcn_update_dpp(xi, xi, 0x138 /*wave_shr:1*/, 0xF, 0xF, false);
  return __int_as_float(r);
}

__global__ __launch_bounds__(64) void zero_kernel(int* __restrict__ cnt) {
  cnt[threadIdx.x] = 0;
}

// ---------------------------------------------------------------------------
// Mega kernel: one dispatch, three block roles; latency-bound DP chains
// overlap the throughput-bound cost tiles:
//   [0, n)              : DP block for matrix mloc = b (spins on cnt[mloc]==16)
//   [n, n+16n)          : cost tile block (matrix-major: mloc = cb>>4)
//   [n+16n, n+16n+ng)   : gram blocks LAST (first chunk only) — they fill CU
//                         slots late, overlapping the DP tail, instead of
//                         squatting in the initial resident set.
// Occupancy fix vs previous round: cost tiles stage A/B in LDS as FP16 ->
// SMEM 68608->34816 B -> 4 blocks/CU (was 2) -> cost phase runs at ~2x waves.
// Gating: cost blocks do syncthreads -> threadfence (agent release) ->
// atomicAdd(cnt+mloc); DP thread0 spins with AGENT-acquire atomic load, then
// threadfence + barrier. Deadlock-free: dp blocks (60) park in 60 of 1024
// slots; progress unconditional.
// ---------------------------------------------------------------------------
__global__ __launch_bounds__(256) void mega_kernel(const float* __restrict__ data,
                                                   const int* __restrict__ lens,
                                                   __half* __restrict__ cost,
                                                   float* __restrict__ sdt,
                                                   float* __restrict__ gram,
                                                   int* __restrict__ cnt,
                                                   int base, int n, int ng) {
  __shared__ __align__(16) char smem[SMEMSZ];
  int b = blockIdx.x;

  if (b >= n && b < n + 16 * n) {
    // ------------------------- cost tile path -------------------------
    int cb = b - n;
    int mloc = cb >> 4, tile = cb & 15;
    int blk = base + mloc;
    int w = blk / NPJ, j = blk - w * NPJ;
    int la = lens[w * STP];
    int lb = lens[w * STP + 1 + j];
    int ti = tile >> 2, tj = tile & 3;
    if (ti * 128 >= la || tj * 128 >= lb) {
      if (threadIdx.x == 0) atomicAdd(&cnt[mloc], 1);   // dead tile: count only
      return;
    }

    __half (*As)[SA] = (__half(*)[SA])smem;
    __half (*Bs)[SA] = (__half(*)[SA])(smem + DD * SA * 2);
    float* a2 = (float*)(smem + 2 * DD * SA * 2);
    float* b2 = a2 + 128;

    const float* A = data + ((size_t)(w * STP) * TT + (size_t)ti * 128) * DD;
    const float* B = data + ((size_t)(w * STP + 1 + j) * TT + (size_t)tj * 128) * DD;
    int t = threadIdx.x;

    #pragma unroll
    for (int i = 0; i < 8; ++i) {
      int idx = t + i * 256;        // [0, 2048)
      int r = idx & 127;            // row within tile
      int kq = idx >> 7;            // float4 index along k, [0,16)
      float4 va = *(const float4*)(A + r * DD + kq * 4);
      As[kq * 4 + 0][r] = __float2half(va.x); As[kq * 4 + 1][r] = __float2half(va.y);
      As[kq * 4 + 2][r] = __float2half(va.z); As[kq * 4 + 3][r] = __float2half(va.w);
      float4 vb = *(const float4*)(B + r * DD + kq * 4);
      Bs[kq * 4 + 0][r] = __float2half(vb.x); Bs[kq * 4 + 1][r] = __float2half(vb.y);
      Bs[kq * 4 + 2][r] = __float2half(vb.z); Bs[kq * 4 + 3][r] = __float2half(vb.w);
    }
    __syncthreads();
    if (t < 128) {
      float s = 0.f;
      for (int k = 0; k < DD; ++k) { float x = __half2float(As[k][t]); s += x * x; }
      a2[t] = s;
    } else {
      float s = 0.f;
      for (int k = 0; k < DD; ++k) { float x = __half2float(Bs[k][t - 128]); s += x * x; }
      b2[t - 128] = s;
    }
    __syncthreads();

    int r0 = (t >> 4) << 2;   // {0,4,...,60}
    int c0 = (t & 15) << 2;   // {0,4,...,60}
    float acc[8][8];
    #pragma unroll
    for (int i = 0; i < 8; ++i)
      #pragma unroll
      for (int q = 0; q < 8; ++q) acc[i][q] = 0.f;

    #pragma unroll 2
    for (int k = 0; k < DD; ++k) {
      const __half2* pAL = (const __half2*)&As[k][r0];
      const __half2* pAH = (const __half2*)&As[k][r0 + 64];
      const __half2* pBL = (const __half2*)&Bs[k][c0];
      const __half2* pBH = (const __half2*)&Bs[k][c0 + 64];
      float2 a0 = __half22float2(pAL[0]), a1 = __half22float2(pAL[1]);
      float2 a2v = __half22float2(pAH[0]), a3 = __half22float2(pAH[1]);
      float2 b0 = __half22float2(pBL[0]), b1 = __half22float2(pBL[1]);
      float2 b2v = __half22float2(pBH[0]), b3 = __half22float2(pBH[1]);
      float a[8] = {a0.x, a0.y, a1.x, a1.y, a2v.x, a2v.y, a3.x, a3.y};
      float bq[8] = {b0.x, b0.y, b1.x, b1.y, b2v.x, b2v.y, b3.x, b3.y};
      #pragma unroll
      for (int i = 0; i < 8; ++i)
        #pragma unroll
        for (int q = 0; q < 8; ++q)
          acc[i][q] += a[i] * bq[q];
    }

    __half* Cbase = cost + (size_t)mloc * CMAT;
    #pragma unroll
    for (int i = 0; i < 8; ++i) {
      int rr = (i < 4) ? (r0 + i) : (r0 + 60 + i);   // r0+64+(i-4)
      float ar = a2[rr];
      __half* Crow = Cbase + (size_t)(ti * 128 + rr) * TT + tj * 128;
      float4 o;
      o.x = (ar + b2[c0 + 0] - 2.f * acc[i][0]) * CSCALE;
      o.y = (ar + b2[c0 + 1] - 2.f * acc[i][1]) * CSCALE;
      o.z = (ar + b2[c0 + 2] - 2.f * acc[i][2]) * CSCALE;
      o.w = (ar + b2[c0 + 3] - 2.f * acc[i][3]) * CSCALE;
      __half2 h01 = __floats2half2_rn(o.x, o.y);
      __half2 h23 = __floats2half2_rn(o.z, o.w);
      uint2 pk; pk.x = *(unsigned*)&h01; pk.y = *(unsigned*)&h23;
      *(uint2*)(Crow + c0) = pk;
      float4 o2;
      o2.x = (ar + b2[c0 + 64] - 2.f * acc[i][4]) * CSCALE;
      o2.y = (ar + b2[c0 + 65] - 2.f * acc[i][5]) * CSCALE;
      o2.z = (ar + b2[c0 + 66] - 2.f * acc[i][6]) * CSCALE;
      o2.w = (ar + b2[c0 + 67] - 2.f * acc[i][7]) * CSCALE;
      __half2 g01 = __floats2half2_rn(o2.x, o2.y);
      __half2 g23 = __floats2half2_rn(o2.z, o2.w);
      uint2 pk2; pk2.x = *(unsigned*)&g01; pk2.y = *(unsigned*)&g23;
      *(uint2*)(Crow + c0 + 64) = pk2;
    }
    __syncthreads();                     // all stores done (barrier drains vmcnt)
    if (threadIdx.x == 0) {
      __threadfence();                   // agent release: flush XCD L2 -> coherent point
      atomicAdd(&cnt[mloc], 1);          // device-scope publish
    }
    return;
  }

  if (b >= n + 16 * n) {
    // ---------------- gram path: 44x44 Gram over K = 32768 ----------------
    float (*red)[16] = (float(*)[16])smem;
    int g = b - n - 16 * n;
    int bx = g / 11, by = g - bx * 11;
    int t = threadIdx.x;
    const float* Ar[4]; const float* Br[4];
    #pragma unroll
    for (int a = 0; a < 4; ++a) {
      int gx = bx * 4 + a;
      Ar[a] = data + (size_t)((gx / 11) * STP + gx % 11) * (TT * DD);
      int gy = by * 4 + a;
      Br[a] = data + (size_t)((gy / 11) * STP + gy % 11) * (TT * DD);
    }
    float acc[4][4];
    #pragma unroll
    for (int a = 0; a < 4; ++a)
      #pragma unroll
      for (int bq = 0; bq < 4; ++bq) acc[a][bq] = 0.f;
    for (int k = t * 4; k < TT * DD; k += 1024) {
      float4 av[4], bv[4];
      #pragma unroll
      for (int a = 0; a < 4; ++a) av[a] = *(const float4*)(Ar[a] + k);
      #pragma unroll
      for (int bq = 0; bq < 4; ++bq) bv[bq] = *(const float4*)(Br[bq] + k);
      #pragma unroll
      for (int a = 0; a < 4; ++a)
        #pragma unroll
        for (int bq = 0; bq < 4; ++bq)
          acc[a][bq] += av[a].x * bv[bq].x + av[a].y * bv[bq].y +
                        av[a].z * bv[bq].z + av[a].w * bv[bq].w;
    }
    int wave = t >> 6, lane = t & 63;
    #pragma unroll
    for (int a = 0; a < 4; ++a)
      #pragma unroll
      for (int bq = 0; bq < 4; ++bq) {
        float v = acc[a][bq];
        for (int off = 32; off > 0; off >>= 1) v += __shfl_down(v, off);
        if (lane == 0) red[wave][a * 4 + bq] = v;
      }
    __syncthreads();
    if (t < 16) {
      float v = red[0][t] + red[1][t] + red[2][t] + red[3][t];
      int a = t >> 2, bq = t & 3;
      gram[(size_t)(bx * 4 + a) * 44 + by * 4 + bq] = v;
    }
    return;
  }

  // -------------------------- DP path --------------------------
  int mloc = b;
  if (threadIdx.x == 0) {
    while (__hip_atomic_load(&cnt[mloc], __ATOMIC_ACQUIRE, __HIP_MEMORY_SCOPE_AGENT) < 16)
      __builtin_amdgcn_s_sleep(2);
  }
  __syncthreads();
  __threadfence();                       // acquire: invalidate stale L1/L2

  float (*bufB)[600] = (float(*)[600])smem;   // boundary columns (write-once)
  int* flags = (int*)(smem + 3 * 600 * 4);

  if (threadIdx.x < 4) flags[threadIdx.x] = 0;
  __syncthreads();

  int blk = base + mloc;
  int w = blk / NPJ, j = blk - w * NPJ;
  int la = lens[w * STP];
  int lb = lens[w * STP + 1 + j];
  const __half* C = cost + (size_t)mloc * CMAT;

  int q = threadIdx.x >> 6, ln = threadIdx.x & 63;
  int c0 = q * 128 + ln * 2;
  const __half* Cp = C + c0;

  // target cell (la-1, lb-1)
  int qt = (lb - 1) >> 7;
  int lt = ((lb - 1) >> 1) & 63;
  int par = (lb - 1) & 1;
  int rt = la - 1;
  bool isT = (q == qt) && (ln == lt);

  float U0 = BIGC, U1 = BIGC;          // own cols, previous row
  float NL = BIGC;                     // left neighbor value, current row
  float NLd = (q == 0 && ln == 0) ? 0.0f : BIGC;  // left-diag (prev row)
  float v1s = BIGC;                    // last computed right-col value
  float res = 0.0f;

  int ngrp = (la + 70) >> 3;

  // cc = current group f32; cn = RAW half2 bits prefetch (no consumer in the
  // prefetch phase -> loads stay in flight; convert at group-end copy)
  float2 cc[8];
  unsigned cn[8];
  #pragma unroll
  for (int k = 0; k < 8; ++k) {
    int rr = k - ln; rr = rr < 0 ? 0 : (rr > 511 ? 511 : rr);
    __half2 hv = *(const __half2*)(Cp + (size_t)rr * TT);
    cc[k] = __half22float2(hv);
  }
  float bb[8];

  for (int g = 0; g < ngrp; ++g) {
    if (q > 0) {
      int need = 8 * g + 9; if (need > la) need = la;
      while (*(volatile int*)&flags[q - 1] < need) __builtin_amdgcn_s_sleep(1);
      asm volatile("s_waitcnt lgkmcnt(0)" ::: "memory");
      #pragma unroll
      for (int k = 0; k < 8; ++k) bb[k] = bufB[q - 1][8 * g + 1 + k];
      if (g == 0) {
        float nl0 = bufB[q - 1][0];
        if (ln == 0) NL = nl0;
      }
    }
    // prefetch RAW bits for next group
    #pragma unroll
    for (int k = 0; k < 8; ++k) {
      int rr = 8 * (g + 1) + k - ln; rr = rr < 0 ? 0 : (rr > 511 ? 511 : rr);
      cn[k] = *(const unsigned*)(Cp + (size_t)rr * TT);
    }
    #pragma unroll
    for (int k = 0; k < 8; ++k) {
      int r = 8 * g + k - ln;
      bool act = ((unsigned)r < 512u);
      if (act) {
        float v0 = dpcell(cc[k].x, NLd, U0, NL);
        float v1 = dpcell(cc[k].y, U0, U1, v0);
        if (isT & (r == rt)) res = par ? v1 : v0;
        NLd = NL; U0 = v0; U1 = v1; v1s = v1;
        if (q < 3 && ln == 63) {
          bufB[q][r] = v1;
          if ((r & 7) == 0) {
            // lane63 hits r%8==0 at k=7 (group end); LDS-only ordering wait
            asm volatile("s_waitcnt lgkmcnt(0)" ::: "memory");
            *(volatile int*)&flags[q] = r + 1;
          }
        }
      }
      float nb = wave_shr1(v1s);
      if (ln == 0) nb = (q == 0) ? BIGC : bb[k];
      NL = nb;
    }
    // group-end: convert raw bits -> f32 (waitcnt lands here, loads are done)
    #pragma unroll
    for (int k = 0; k < 8; ++k) {
      __half2 hv = *(__half2*)&cn[k];
      cc[k] = __half22float2(hv);
    }
  }
  if (q < 3 && ln == 63) {
    asm volatile("s_waitcnt lgkmcnt(0)" ::: "memory");
    *(volatile int*)&flags[q] = 512;   // release any remaining pollers
  }
  if (isT) sdt[blk] = res * USCALE;
}

// ---------------------------------------------------------------------------
// Final combine. block 640 = 10 waves; waves 0..8: one MMD pair each;
// wave 9: triplet losses; thread 0 writes the scalar.
// ---------------------------------------------------------------------------
__global__ __launch_bounds__(640) void final_kernel(const float* __restrict__ sdt,
                                                    const int* __restrict__ lens,
                                                    const float* __restrict__ gram,
                                                    float* __restrict__ out) {
  __shared__ float partial[16];
  int t = threadIdx.x, wave = t >> 6, lane = t & 63;
  if (wave < 9) {
    const int piA[9] = {0, 0, 0, 1, 1, 2, 2, 3, 3};
    const int pjA[9] = {1, 2, 3, 2, 3, 1, 3, 1, 2};
    int P = piA[wave], Q = pjA[wave];
    float s1 = 0.f;
    for (int c = lane; c < 484; c += 64) {
      int i = c / 22, jj = c - (c / 22) * 22;
      int gi = (i < 11) ? P * 11 + i : Q * 11 + (i - 11);
      int gj = (jj < 11) ? P * 11 + jj : Q * 11 + (jj - 11);
      s1 += gram[gi * 44 + gi] + gram[gj * 44 + gj] - 2.f * gram[gi * 44 + gj];
    }
    for (int off = 32; off > 0; off >>= 1) s1 += __shfl_down(s1, off);
    s1 = __shfl(s1, 0);
    float bw = s1 / 462.0f * 0.25f;     // /(ns^2-ns) then / KMUL^(KNUM//2)=4
    float inv[5];
    float b = bw;
    #pragma unroll
    for (int qq = 0; qq < 5; ++qq) { inv[qq] = -1.0f / b; b *= 2.0f; }
    float s2 = 0.f;
    for (int c = lane; c < 484; c += 64) {
      int i = c / 22, jj = c - (c / 22) * 22;
      int gi = (i < 11) ? P * 11 + i : Q * 11 + (i - 11);
      int gj = (jj < 11) ? P * 11 + jj : Q * 11 + (jj - 11);
      float l2 = gram[gi * 44 + gi] + gram[gj * 44 + gj] - 2.f * gram[gi * 44 + gj];
      float kk = 0.f;
      #pragma unroll
      for (int qq = 0; qq < 5; ++qq) kk += __expf(l2 * inv[qq]);
      float sgn = ((i < 11) == (jj < 11)) ? 1.0f : -1.0f;
      s2 += sgn * kk;
    }
    for (int off = 32; off > 0; off >>= 1) s2 += __shfl_down(s2, off);
    if (lane == 0) partial[wave] = s2 / 121.0f;
  } else {
    float term = 0.f;
    if (wave == 9 && lane < 4) {
      int w = lane;
      float L0 = (float)lens[w * STP];
      float dist[15];
      for (int qq = 0; qq < 15; ++qq)
        dist[qq] = sdt[w * NPJ + qq] / (L0 + (float)lens[w * STP + 1 + qq]);
      float ca = 0.f, cb = 0.f;
      for (int a = 0; a < 6; ++a) ca += dist[a];
      ca *= (1.0f / 6.0f);
      for (int bq = 6; bq < 11; ++bq) cb += dist[bq];
      cb *= (1.0f / 5.0f);
      float lksum = 0.f; int nz = 0;
      for (int a = 0; a < 6; ++a)
        for (int bq = 6; bq < 15; ++bq) {
          float x = dist[a] + 1.0f - dist[bq];   // MARGIN = 1.0
          if (x > 0.f) { lksum += x; nz += 1; }
        }
      float intra = 0.f;
      for (int a = 0; a < 6; ++a) intra += dist[a] - ca;
      float inter = fmaxf(0.f, 1.0f - fabsf(ca - cb));  // BETA = 1.0
      term = lksum / (float)(nz + 1) + intra * 0.1f + inter * 0.1f;  // P=R=0.1
    }
    if (wave == 9) {
      term += __shfl_down(term, 1);
      term += __shfl_down(term, 2);
      if (lane == 0) partial[9] = term * 0.25f;   // mean over NW=4
    }
  }
  __syncthreads();
  if (t == 0) {
    float mx = 0.0f;                               // zero-pad in the max
    for (int p = 0; p < 9; ++p) mx = fmaxf(mx, partial[p]);
    out[0] = partial[9] + 0.01f * mx;              // ALPHA = 0.01
  }
}

// ---------------------------------------------------------------------------
extern "C" void kernel_launch(void* const* d_in, const int* in_sizes, int n_in,
                              void* d_out, int out_size, void* d_ws, size_t ws_size,
                              hipStream_t stream) {
  const float* data = (const float*)d_in[0];
  const int* lens = (const int*)d_in[1];
  float* out = (float*)d_out;

  float* sdtb  = (float*)d_ws;                      // 64 floats
  float* gramb = sdtb + 64;                         // 44*44 = 1936 floats (ends @ 8000B)
  int*   cntb  = (int*)((char*)d_ws + 8192);        // 64 ints
  __half* costh = (__half*)((char*)d_ws + 8448);    // fp16 cost matrices

  size_t avail = (ws_size > 8448) ? (ws_size - 8448) : 0;
  int chunk = (int)(avail / ((size_t)CMAT * sizeof(__half)));
  if (chunk < 1) chunk = 1;
  if (chunk > NBLK) chunk = NBLK;

  bool first = true;
  for (int base = 0; base < NBLK; base += chunk) {
    int n = NBLK - base;
    if (n > chunk) n = chunk;
    int ng = first ? 121 : 0;
    zero_kernel<<<1, 64, 0, stream>>>(cntb);
    mega_kernel<<<n + 16 * n + ng, 256, 0, stream>>>(data, lens, costh, sdtb, gramb,
                                                     cntb, base, n, ng);
    first = false;
  }
  final_kernel<<<1, 640, 0, stream>>>(sdtb, lens, gramb, out);
}

// Round 15
// 197.465 us; speedup vs baseline: 1.2417x; 1.2127x over previous
//
#include <hip/hip_runtime.h>
#include <hip/hip_bf16.h>

// Problem constants
#define TT   512
#define DD   64
#define NWK  4
#define STP  16
#define NPJ  15          // others per w
#define NBLK 60          // NWK * NPJ
#define CMAT (TT * TT)   // floats per cost matrix
// u-domain scale: u = R / (gamma * ln2), gamma = 5
#define CSCALE 0.2885390081777927f
#define USCALE 3.4657359027997265f   // gamma * ln2
#define BIGC   2.885390081777927e8f  // 1e9 * CSCALE

#define SA 132   // LDS leading stride (128 + 4 pad)

// ---------------------------------------------------------------------------
// Kernel 1: cost matrices, scaled by CSCALE. 128x128 tile per block, 256 thr,
// split 4+4 register tile per thread (rows {r0..r0+3, r0+64..67} x cols same)
// so every ds_read_b128 is <=2-way bank-aliased (free). grid (4,4,n).
// ---------------------------------------------------------------------------
__global__ __launch_bounds__(256) void cost_kernel(const float* __restrict__ data,
                                                   const int* __restrict__ lens,
                                                   float* __restrict__ cost, int base) {
  int blk = base + blockIdx.z;
  int w = blk / NPJ, j = blk - w * NPJ;
  int la = lens[w * STP];
  int lb = lens[w * STP + 1 + j];
  int ti = blockIdx.y, tj = blockIdx.x;
  if (ti * 128 >= la || tj * 128 >= lb) return;

  __shared__ float As[DD][SA];   // k-major: As[k][r], r in [0,128)
  __shared__ float Bs[DD][SA];
  __shared__ float a2[128], b2[128];

  const float* A = data + ((size_t)(w * STP) * TT + (size_t)ti * 128) * DD;
  const float* B = data + ((size_t)(w * STP + 1 + j) * TT + (size_t)tj * 128) * DD;
  int t = threadIdx.x;

  #pragma unroll
  for (int i = 0; i < 8; ++i) {
    int idx = t + i * 256;        // [0, 2048)
    int r = idx & 127;            // row within tile
    int kq = idx >> 7;            // float4 index along k, [0,16)
    float4 va = *(const float4*)(A + r * DD + kq * 4);
    As[kq * 4 + 0][r] = va.x; As[kq * 4 + 1][r] = va.y;
    As[kq * 4 + 2][r] = va.z; As[kq * 4 + 3][r] = va.w;
    float4 vb = *(const float4*)(B + r * DD + kq * 4);
    Bs[kq * 4 + 0][r] = vb.x; Bs[kq * 4 + 1][r] = vb.y;
    Bs[kq * 4 + 2][r] = vb.z; Bs[kq * 4 + 3][r] = vb.w;
  }
  __syncthreads();
  if (t < 128) {
    float s = 0.f;
    for (int k = 0; k < DD; ++k) { float x = As[k][t]; s += x * x; }
    a2[t] = s;
  } else {
    float s = 0.f;
    for (int k = 0; k < DD; ++k) { float x = Bs[k][t - 128]; s += x * x; }
    b2[t - 128] = s;
  }
  __syncthreads();

  int r0 = (t >> 4) << 2;   // {0,4,...,60}
  int c0 = (t & 15) << 2;   // {0,4,...,60}
  float acc[8][8];
  #pragma unroll
  for (int i = 0; i < 8; ++i)
    #pragma unroll
    for (int q = 0; q < 8; ++q) acc[i][q] = 0.f;

  #pragma unroll 2
  for (int k = 0; k < DD; ++k) {
    float4 aL = *(const float4*)&As[k][r0];
    float4 aH = *(const float4*)&As[k][r0 + 64];
    float4 bL = *(const float4*)&Bs[k][c0];
    float4 bH = *(const float4*)&Bs[k][c0 + 64];
    float a[8] = {aL.x, aL.y, aL.z, aL.w, aH.x, aH.y, aH.z, aH.w};
    float b[8] = {bL.x, bL.y, bL.z, bL.w, bH.x, bH.y, bH.z, bH.w};
    #pragma unroll
    for (int i = 0; i < 8; ++i)
      #pragma unroll
      for (int q = 0; q < 8; ++q)
        acc[i][q] += a[i] * b[q];
  }

  float* Cbase = cost + (size_t)blockIdx.z * CMAT;
  #pragma unroll
  for (int i = 0; i < 8; ++i) {
    int rr = (i < 4) ? (r0 + i) : (r0 + 60 + i);   // r0+64+(i-4)
    float ar = a2[rr];
    float* Crow = Cbase + (size_t)(ti * 128 + rr) * TT + tj * 128;
    float4 o;
    o.x = (ar + b2[c0 + 0] - 2.f * acc[i][0]) * CSCALE;
    o.y = (ar + b2[c0 + 1] - 2.f * acc[i][1]) * CSCALE;
    o.z = (ar + b2[c0 + 2] - 2.f * acc[i][2]) * CSCALE;
    o.w = (ar + b2[c0 + 3] - 2.f * acc[i][3]) * CSCALE;
    *(float4*)(Crow + c0) = o;
    float4 o2;
    o2.x = (ar + b2[c0 + 64] - 2.f * acc[i][4]) * CSCALE;
    o2.y = (ar + b2[c0 + 65] - 2.f * acc[i][5]) * CSCALE;
    o2.z = (ar + b2[c0 + 66] - 2.f * acc[i][6]) * CSCALE;
    o2.w = (ar + b2[c0 + 67] - 2.f * acc[i][7]) * CSCALE;
    *(float4*)(Crow + c0 + 64) = o2;
  }
}

// ---------------------------------------------------------------------------
// Soft-DTW DP cell in u-units: u = dc + min - log2(1 + 2^(min-med) + 2^(min-max))
// ---------------------------------------------------------------------------
__device__ __forceinline__ float dpcell(float dc, float a, float b, float c) {
  float mn = fminf(fminf(a, b), c);
  float mx = fmaxf(fmaxf(a, b), c);
  float md = __builtin_amdgcn_fmed3f(a, b, c);
  float e = 1.0f + __builtin_amdgcn_exp2f(mn - md) + __builtin_amdgcn_exp2f(mn - mx);
  return dc + mn - __builtin_amdgcn_logf(e);
}

// DPP wave_shr:1 — VALU-latency replacement for __shfl_up(x, 1).
// Lanes 1..63 receive lane-1's value; lane 0 keeps its own (bound_ctrl=false),
// which matches __shfl_up semantics (lane 0 is overwritten by caller anyway).
__device__ __forceinline__ float wave_shr1(float x) {
  int xi = __float_as_int(x);
  int r = __builtin_amdgcn_update_dpp(xi, xi, 0x138 /*wave_shr:1*/, 0xF, 0xF, false);
  return __int_as_float(r);
}

// ---------------------------------------------------------------------------
// Kernel 2: fused DP (blocks [0,ndp)) + gram (blocks [ndp, ndp+121)).
// DP: barrier-free systolic pipeline — round-11 champion structure (4 waves;
// wave q owns cols [128q,128q+128); lane owns 2 cols, lane-skew 1 row/lane;
// DPP intra-wave boundary; write-once LDS column + spin flags inter-wave;
// publish at (r&7)==0 -> flag 8g+9 meets need exactly; lgkm-only fences).
// NEW: the group loop is split fill (g<8) / STEADY (8<=g<64) / drain.
// In steady groups every lane has r = 8g+k-ln in [1,511] -> the per-lane
// divergent `act` guard is provably all-true; the steady body drops it,
// removing vcmp+saveexec+cbranch serialization from ~78% of the ~576 steps
// of this latency-bound chain. Per-cell arithmetic identical -> bit-identical.
// ---------------------------------------------------------------------------
__global__ __launch_bounds__(256) void dp_gram_kernel(const float* __restrict__ cost,
                                                      const int* __restrict__ lens,
                                                      const float* __restrict__ data,
                                                      float* __restrict__ sdt,
                                                      float* __restrict__ gram,
                                                      int base, int ndp) {
  int bid = blockIdx.x;

  if (bid >= ndp) {
    // ---------------- gram path: 44x44 Gram over K = 32768 ----------------
    __shared__ float red[4][16];
    int g = bid - ndp;
    int bx = g / 11, by = g - bx * 11;
    int t = threadIdx.x;
    const float* Ar[4]; const float* Br[4];
    #pragma unroll
    for (int a = 0; a < 4; ++a) {
      int gx = bx * 4 + a;
      Ar[a] = data + (size_t)((gx / 11) * STP + gx % 11) * (TT * DD);
      int gy = by * 4 + a;
      Br[a] = data + (size_t)((gy / 11) * STP + gy % 11) * (TT * DD);
    }
    float acc[4][4];
    #pragma unroll
    for (int a = 0; a < 4; ++a)
      #pragma unroll
      for (int b = 0; b < 4; ++b) acc[a][b] = 0.f;
    for (int k = t * 4; k < TT * DD; k += 1024) {
      float4 av[4], bv[4];
      #pragma unroll
      for (int a = 0; a < 4; ++a) av[a] = *(const float4*)(Ar[a] + k);
      #pragma unroll
      for (int b = 0; b < 4; ++b) bv[b] = *(const float4*)(Br[b] + k);
      #pragma unroll
      for (int a = 0; a < 4; ++a)
        #pragma unroll
        for (int b = 0; b < 4; ++b)
          acc[a][b] += av[a].x * bv[b].x + av[a].y * bv[b].y +
                       av[a].z * bv[b].z + av[a].w * bv[b].w;
    }
    int wave = t >> 6, lane = t & 63;
    #pragma unroll
    for (int a = 0; a < 4; ++a)
      #pragma unroll
      for (int b = 0; b < 4; ++b) {
        float v = acc[a][b];
        for (int off = 32; off > 0; off >>= 1) v += __shfl_down(v, off);
        if (lane == 0) red[wave][a * 4 + b] = v;
      }
    __syncthreads();
    if (t < 16) {
      float v = red[0][t] + red[1][t] + red[2][t] + red[3][t];
      int a = t >> 2, b = t & 3;
      gram[(size_t)(bx * 4 + a) * 44 + by * 4 + b] = v;
    }
    return;
  }

  // -------------------------- DP path --------------------------
  __shared__ float bufB[3][600];   // boundary column per wave (write-once)
  __shared__ int flags[4];

  if (threadIdx.x < 4) flags[threadIdx.x] = 0;
  __syncthreads();

  int blk = base + bid;
  int w = blk / NPJ, j = blk - w * NPJ;
  int la = lens[w * STP];
  int lb = lens[w * STP + 1 + j];
  const float* C = cost + (size_t)bid * CMAT;

  int q = threadIdx.x >> 6, ln = threadIdx.x & 63;
  int c0 = q * 128 + ln * 2;
  const float* Cp = C + c0;

  // target cell (la-1, lb-1)
  int qt = (lb - 1) >> 7;
  int lt = ((lb - 1) >> 1) & 63;
  int par = (lb - 1) & 1;
  int rt = la - 1;
  bool isT = (q == qt) && (ln == lt);

  float U0 = BIGC, U1 = BIGC;          // own cols, previous row
  float NL = BIGC;                     // left neighbor value, current row
  float NLd = (q == 0 && ln == 0) ? 0.0f : BIGC;  // left-diag (prev row)
  float v1s = BIGC;                    // last computed right-col value
  float res = 0.0f;

  int ngrp = (la + 70) >> 3;

  // cost regs: cc = current group (rows 8g+k-ln), cn = next group prefetch
  float2 cc[8], cn[8];
  #pragma unroll
  for (int k = 0; k < 8; ++k) {
    int rr = k - ln; rr = rr < 0 ? 0 : (rr > 511 ? 511 : rr);
    cc[k] = *(const float2*)(Cp + (size_t)rr * TT);
  }
  float bb[8];

  for (int g = 0; g < ngrp; ++g) {
    if (q > 0) {
      int need = 8 * g + 9; if (need > la) need = la;
      while (*(volatile int*)&flags[q - 1] < need) __builtin_amdgcn_s_sleep(1);
      asm volatile("s_waitcnt lgkmcnt(0)" ::: "memory");
      #pragma unroll
      for (int k = 0; k < 8; ++k) bb[k] = bufB[q - 1][8 * g + 1 + k];
      if (g == 0) {
        float nl0 = bufB[q - 1][0];
        if (ln == 0) NL = nl0;
      }
    }
    // prefetch cost for next group (clamped rows; stays in flight this group)
    #pragma unroll
    for (int k = 0; k < 8; ++k) {
      int rr = 8 * (g + 1) + k - ln; rr = rr < 0 ? 0 : (rr > 511 ? 511 : rr);
      cn[k] = *(const float2*)(Cp + (size_t)rr * TT);
    }
    if (g >= 8 && g < 64) {
      // ---- STEADY: r = 8g+k-ln in [1,511] for every lane -> no act guard ----
      #pragma unroll
      for (int k = 0; k < 8; ++k) {
        int r = 8 * g + k - ln;
        float v0 = dpcell(cc[k].x, NLd, U0, NL);
        float v1 = dpcell(cc[k].y, U0, U1, v0);
        if (isT & (r == rt)) res = par ? v1 : v0;
        NLd = NL; U0 = v0; U1 = v1; v1s = v1;
        if (q < 3 && ln == 63) {
          bufB[q][r] = v1;
          if ((r & 7) == 0) {
            // order bufB write before flag write; LDS-only wait (no vmcnt
            // drain). For lane63, r%8==0 occurs at k=7 — group end.
            asm volatile("s_waitcnt lgkmcnt(0)" ::: "memory");
            *(volatile int*)&flags[q] = r + 1;
          }
        }
        float nb = wave_shr1(v1s);
        if (ln == 0) nb = (q == 0) ? BIGC : bb[k];
        NL = nb;
      }
    } else {
      // ---- fill / drain: per-lane act guard as before ----
      #pragma unroll
      for (int k = 0; k < 8; ++k) {
        int r = 8 * g + k - ln;
        bool act = ((unsigned)r < 512u);
        if (act) {
          float v0 = dpcell(cc[k].x, NLd, U0, NL);
          float v1 = dpcell(cc[k].y, U0, U1, v0);
          if (isT & (r == rt)) res = par ? v1 : v0;
          NLd = NL; U0 = v0; U1 = v1; v1s = v1;
          if (q < 3 && ln == 63) {
            bufB[q][r] = v1;
            if ((r & 7) == 0) {
              asm volatile("s_waitcnt lgkmcnt(0)" ::: "memory");
              *(volatile int*)&flags[q] = r + 1;
            }
          }
        }
        float nb = wave_shr1(v1s);
        if (ln == 0) nb = (q == 0) ? BIGC : bb[k];
        NL = nb;
      }
    }
    #pragma unroll
    for (int k = 0; k < 8; ++k) cc[k] = cn[k];
  }
  if (q < 3 && ln == 63) {
    asm volatile("s_waitcnt lgkmcnt(0)" ::: "memory");
    *(volatile int*)&flags[q] = 512;   // release any remaining pollers
  }
  if (isT) sdt[blk] = res * USCALE;
}

// ---------------------------------------------------------------------------
// Kernel 4: final combine. block 640 = 10 waves; waves 0..8: one MMD pair each;
// wave 9: triplet losses; thread 0 writes the scalar.
// ---------------------------------------------------------------------------
__global__ __launch_bounds__(640) void final_kernel(const float* __restrict__ sdt,
                                                    const int* __restrict__ lens,
                                                    const float* __restrict__ gram,
                                                    float* __restrict__ out) {
  __shared__ float partial[16];
  int t = threadIdx.x, wave = t >> 6, lane = t & 63;
  if (wave < 9) {
    const int piA[9] = {0, 0, 0, 1, 1, 2, 2, 3, 3};
    const int pjA[9] = {1, 2, 3, 2, 3, 1, 3, 1, 2};
    int P = piA[wave], Q = pjA[wave];
    float s1 = 0.f;
    for (int c = lane; c < 484; c += 64) {
      int i = c / 22, jj = c - (c / 22) * 22;
      int gi = (i < 11) ? P * 11 + i : Q * 11 + (i - 11);
      int gj = (jj < 11) ? P * 11 + jj : Q * 11 + (jj - 11);
      s1 += gram[gi * 44 + gi] + gram[gj * 44 + gj] - 2.f * gram[gi * 44 + gj];
    }
    for (int off = 32; off > 0; off >>= 1) s1 += __shfl_down(s1, off);
    s1 = __shfl(s1, 0);
    float bw = s1 / 462.0f * 0.25f;     // /(ns^2-ns) then / KMUL^(KNUM//2)=4
    float inv[5];
    float b = bw;
    #pragma unroll
    for (int qq = 0; qq < 5; ++qq) { inv[qq] = -1.0f / b; b *= 2.0f; }
    float s2 = 0.f;
    for (int c = lane; c < 484; c += 64) {
      int i = c / 22, jj = c - (c / 22) * 22;
      int gi = (i < 11) ? P * 11 + i : Q * 11 + (i - 11);
      int gj = (jj < 11) ? P * 11 + jj : Q * 11 + (jj - 11);
      float l2 = gram[gi * 44 + gi] + gram[gj * 44 + gj] - 2.f * gram[gi * 44 + gj];
      float kk = 0.f;
      #pragma unroll
      for (int qq = 0; qq < 5; ++qq) kk += __expf(l2 * inv[qq]);
      float sgn = ((i < 11) == (jj < 11)) ? 1.0f : -1.0f;
      s2 += sgn * kk;
    }
    for (int off = 32; off > 0; off >>= 1) s2 += __shfl_down(s2, off);
    if (lane == 0) partial[wave] = s2 / 121.0f;
  } else {
    float term = 0.f;
    if (wave == 9 && lane < 4) {
      int w = lane;
      float L0 = (float)lens[w * STP];
      float dist[15];
      for (int qq = 0; qq < 15; ++qq)
        dist[qq] = sdt[w * NPJ + qq] / (L0 + (float)lens[w * STP + 1 + qq]);
      float ca = 0.f, cb = 0.f;
      for (int a = 0; a < 6; ++a) ca += dist[a];
      ca *= (1.0f / 6.0f);
      for (int bq = 6; bq < 11; ++bq) cb += dist[bq];
      cb *= (1.0f / 5.0f);
      float lksum = 0.f; int nz = 0;
      for (int a = 0; a < 6; ++a)
        for (int bq = 6; bq < 15; ++bq) {
          float x = dist[a] + 1.0f - dist[bq];   // MARGIN = 1.0
          if (x > 0.f) { lksum += x; nz += 1; }
        }
      float intra = 0.f;
      for (int a = 0; a < 6; ++a) intra += dist[a] - ca;
      float inter = fmaxf(0.f, 1.0f - fabsf(ca - cb));  // BETA = 1.0
      term = lksum / (float)(nz + 1) + intra * 0.1f + inter * 0.1f;  // P=R=0.1
    }
    if (wave == 9) {
      term += __shfl_down(term, 1);
      term += __shfl_down(term, 2);
      if (lane == 0) partial[9] = term * 0.25f;   // mean over NW=4
    }
  }
  __syncthreads();
  if (t == 0) {
    float mx = 0.0f;                               // zero-pad in the max
    for (int p = 0; p < 9; ++p) mx = fmaxf(mx, partial[p]);
    out[0] = partial[9] + 0.01f * mx;              // ALPHA = 0.01
  }
}

// ---------------------------------------------------------------------------
extern "C" void kernel_launch(void* const* d_in, const int* in_sizes, int n_in,
                              void* d_out, int out_size, void* d_ws, size_t ws_size,
                              hipStream_t stream) {
  const float* data = (const float*)d_in[0];
  const int* lens = (const int*)d_in[1];
  float* out = (float*)d_out;

  float* sdtb  = (float*)d_ws;                      // 60 floats
  float* gramb = sdtb + 64;                         // 44*44 floats
  float* costb = (float*)((char*)d_ws + 8192);      // cost chunks

  size_t avail = (ws_size > 8192) ? (ws_size - 8192) : 0;
  int chunk = (int)(avail / ((size_t)CMAT * sizeof(float)));
  if (chunk < 1) chunk = 1;
  if (chunk > NBLK) chunk = NBLK;

  bool first = true;
  for (int base = 0; base < NBLK; base += chunk) {
    int n = NBLK - base;
    if (n > chunk) n = chunk;
    cost_kernel<<<dim3(4, 4, n), 256, 0, stream>>>(data, lens, costb, base);
    int extra = first ? 121 : 0;   // fuse gram onto otherwise-idle CUs
    dp_gram_kernel<<<n + extra, 256, 0, stream>>>(costb, lens, data, sdtb, gramb, base, n);
    first = false;
  }
  final_kernel<<<1, 640, 0, stream>>>(sdtb, lens, gramb, out);
}